// Round 10
// baseline (302.201 us; speedup 1.0000x reference)
//
#include <hip/hip_runtime.h>
#include <hip/hip_bf16.h>

#define EMB 768
#define HD 96
#define NH 8
#define SEQ 2048
#define SCALING 0.10206207261596575f   // 96^-0.5

typedef short bf16x8 __attribute__((ext_vector_type(8)));
typedef float f32x4  __attribute__((ext_vector_type(4)));
typedef unsigned short u16v8 __attribute__((ext_vector_type(8)));
typedef unsigned short u16v4 __attribute__((ext_vector_type(4)));

union F4 { float4 v; float f[4]; };

__device__ __forceinline__ unsigned short f2bf(float v) {
    __hip_bfloat16 b = __float2bfloat16(v);
    return *reinterpret_cast<unsigned short*>(&b);
}
__device__ __forceinline__ float bf2f(unsigned short u) {
    __hip_bfloat16 b = *reinterpret_cast<__hip_bfloat16*>(&u);
    return __bfloat162float(b);
}

// async global->LDS DMA, 16 B/lane. LDS dest = wave-uniform base + lane*16.
__device__ __forceinline__ void dma16(const unsigned short* g, unsigned short* l) {
    __builtin_amdgcn_global_load_lds(
        (const __attribute__((address_space(1))) unsigned int*)g,
        (__attribute__((address_space(3))) unsigned int*)l,
        16, 0, 0);
}

// ---------------------------------------------------------------------------
// convert_x: fp32 x -> hi/lo bf16 arrays [4096][768].
// ---------------------------------------------------------------------------
__global__ __launch_bounds__(256) void convert_x(
    const float* __restrict__ x,
    unsigned short* __restrict__ xh, unsigned short* __restrict__ xl)
{
    const size_t i0 = ((size_t)blockIdx.x * 256 + threadIdx.x) * 8;
    F4 a, b;
    a.v = *(const float4*)&x[i0];
    b.v = *(const float4*)&x[i0 + 4];
    u16v8 h, l;
    #pragma unroll
    for (int j = 0; j < 4; j++) {
        unsigned short hu = f2bf(a.f[j]);
        h[j] = hu; l[j] = f2bf(a.f[j] - bf2f(hu));
    }
    #pragma unroll
    for (int j = 0; j < 4; j++) {
        unsigned short hu = f2bf(b.f[j]);
        h[4+j] = hu; l[4+j] = f2bf(b.f[j] - bf2f(hu));
    }
    *(u16v8*)&xh[i0] = h;
    *(u16v8*)&xl[i0] = l;
}

// ---------------------------------------------------------------------------
// convert_wT: W [768 k][768 n] fp32 -> W^T hi/lo bf16 [mat][768 n][768 k].
// ---------------------------------------------------------------------------
__global__ __launch_bounds__(256) void convert_wT(
    const float* __restrict__ Wq, const float* __restrict__ Wk,
    const float* __restrict__ Wv, const float* __restrict__ Wo,
    unsigned short* __restrict__ WhT, unsigned short* __restrict__ WlT)
{
    const int z = blockIdx.z;
    const float* W = (z == 0) ? Wq : (z == 1) ? Wk : (z == 2) ? Wv : Wo;
    unsigned short* oh = WhT + (size_t)z * 589824;
    unsigned short* ol = WlT + (size_t)z * 589824;
    __shared__ float T[64][68];
    const int t = threadIdx.x;
    const int r = t >> 2, cg = (t & 3) * 16;
    const int k0 = blockIdx.x * 64, n0 = blockIdx.y * 64;
    #pragma unroll
    for (int i = 0; i < 4; i++) {
        float4 v = *(const float4*)&W[(size_t)(k0 + r) * EMB + n0 + cg + 4*i];
        *(float4*)&T[r][cg + 4*i] = v;
    }
    __syncthreads();
    #pragma unroll
    for (int i = 0; i < 4; i++) {
        u16v4 h, l;
        #pragma unroll
        for (int j = 0; j < 4; j++) {
            float v = T[cg + 4*i + j][r];
            unsigned short hu = f2bf(v);
            h[j] = hu; l[j] = f2bf(v - bf2f(hu));
        }
        *(u16v4*)&oh[(size_t)(n0 + r) * EMB + k0 + cg + 4*i] = h;
        *(u16v4*)&ol[(size_t)(n0 + r) * EMB + k0 + cg + 4*i] = l;
    }
}

// ---------------------------------------------------------------------------
// qkv_mfma v2 (unchanged from R9): global_load_lds staging, 128x128, BK=32.
// Q (z=0): 3-term -> hi/lo bf16 out. K (z=1): 2-term -> single bf16.
// V (z=2): 2-term -> bf16 transposed [bh][d][s].
// ---------------------------------------------------------------------------
#define QA_H 0
#define QA_L 4096
#define QW_H 8192
#define QW_L 12288

__global__ __launch_bounds__(256, 3) void qkv_mfma(
    const unsigned short* __restrict__ xh, const unsigned short* __restrict__ xl,
    const unsigned short* __restrict__ WhT, const unsigned short* __restrict__ WlT,
    const float* __restrict__ bq, const float* __restrict__ bk, const float* __restrict__ bv,
    unsigned short* __restrict__ Qh, unsigned short* __restrict__ Ql,
    unsigned short* __restrict__ Kb, unsigned short* __restrict__ Vt)
{
    const int which = blockIdx.z;
    const unsigned short* Wh = WhT + (size_t)which * 589824;
    const unsigned short* Wl = WlT + (size_t)which * 589824;
    const float* bias = (which == 0) ? bq : (which == 1) ? bk : bv;

    __shared__ __align__(16) unsigned short lds[16384];
    const int tid = threadIdx.x;
    const int lane = tid & 63, lo = lane & 15, h4 = lane >> 4;
    const int w = tid >> 6, wm = w & 1, wn = w >> 1;
    const int row0 = blockIdx.x * 128, col0 = blockIdx.y * 128;

    const unsigned short* sbase =
        (w == 0) ? xh + (size_t)row0 * EMB :
        (w == 1) ? xl + (size_t)row0 * EMB :
        (w == 2) ? Wh + (size_t)col0 * EMB :
                   Wl + (size_t)col0 * EMB;
    const int soff = w * 4096;

    f32x4 acc[4][4];
    #pragma unroll
    for (int i = 0; i < 4; i++)
        #pragma unroll
        for (int j = 0; j < 4; j++) acc[i][j] = (f32x4){0.f, 0.f, 0.f, 0.f};

    for (int k0 = 0; k0 < EMB; k0 += 32) {
        #pragma unroll
        for (int j = 0; j < 8; j++) {
            const int u = j*64 + lane;
            const int row = u >> 2, c8 = (u & 3) * 8;
            dma16(sbase + (size_t)row * EMB + k0 + c8, &lds[soff + j*512]);
        }
        __syncthreads();

        bf16x8 ah[4], al[4];
        #pragma unroll
        for (int i = 0; i < 4; i++)
            ah[i] = *(const bf16x8*)&lds[QA_H + (64*wm + 16*i + lo)*32 + 8*h4];
        if (which <= 1) {
            #pragma unroll
            for (int i = 0; i < 4; i++)
                al[i] = *(const bf16x8*)&lds[QA_L + (64*wm + 16*i + lo)*32 + 8*h4];
        }
        #pragma unroll
        for (int j = 0; j < 4; j++) {
            bf16x8 whf = *(const bf16x8*)&lds[QW_H + (64*wn + 16*j + lo)*32 + 8*h4];
            #pragma unroll
            for (int i = 0; i < 4; i++)
                acc[i][j] = __builtin_amdgcn_mfma_f32_16x16x32_bf16(ah[i], whf, acc[i][j], 0, 0, 0);
            if (which <= 1) {
                #pragma unroll
                for (int i = 0; i < 4; i++)
                    acc[i][j] = __builtin_amdgcn_mfma_f32_16x16x32_bf16(al[i], whf, acc[i][j], 0, 0, 0);
            }
            if (which != 1) {
                bf16x8 wlf = *(const bf16x8*)&lds[QW_L + (64*wn + 16*j + lo)*32 + 8*h4];
                #pragma unroll
                for (int i = 0; i < 4; i++)
                    acc[i][j] = __builtin_amdgcn_mfma_f32_16x16x32_bf16(ah[i], wlf, acc[i][j], 0, 0, 0);
            }
        }
        __syncthreads();
    }

    if (which == 0) {
        #pragma unroll
        for (int i = 0; i < 4; i++)
            #pragma unroll
            for (int r = 0; r < 4; r++) {
                const int sg = row0 + 64*wm + 16*i + 4*h4 + r;
                const int b = sg >> 11, s = sg & 2047;
                #pragma unroll
                for (int j = 0; j < 4; j++) {
                    const int c = col0 + 64*wn + 16*j + lo;
                    const int h = c / HD, d = c - h*HD;
                    float v = acc[i][j][r] + bias[c];
                    unsigned short hu = f2bf(v);
                    const size_t base = ((size_t)(b*NH + h) * SEQ + s) * HD + d;
                    Qh[base] = hu;
                    Ql[base] = f2bf(v - bf2f(hu));
                }
            }
    } else if (which == 1) {
        #pragma unroll
        for (int i = 0; i < 4; i++)
            #pragma unroll
            for (int r = 0; r < 4; r++) {
                const int sg = row0 + 64*wm + 16*i + 4*h4 + r;
                const int b = sg >> 11, s = sg & 2047;
                #pragma unroll
                for (int j = 0; j < 4; j++) {
                    const int c = col0 + 64*wn + 16*j + lo;
                    const int h = c / HD, d = c - h*HD;
                    float v = acc[i][j][r] + bias[c];
                    Kb[((size_t)(b*NH + h) * SEQ + s) * HD + d] = f2bf(v);
                }
            }
    } else {
        #pragma unroll
        for (int i = 0; i < 4; i++)
            #pragma unroll
            for (int r = 0; r < 4; r++) {
                const int sg = row0 + 64*wm + 16*i + 4*h4 + r;
                const int b = sg >> 11, s = sg & 2047;
                #pragma unroll
                for (int j = 0; j < 4; j++) {
                    const int c = col0 + 64*wn + 16*j + lo;
                    const int h = c / HD, d = c - h*HD;
                    float v = acc[i][j][r] + bias[c];
                    Vt[((size_t)(b*NH + h) * HD + d) * SEQ + s] = f2bf(v);
                }
            }
    }
}

// ---------------------------------------------------------------------------
// proj_mfma v2 (unchanged from R9): 128x64 tile, DMA staging, 2-term.
// ---------------------------------------------------------------------------
#define PA_O 0
#define PWH_O 4096
#define PWL_O 6144

__global__ __launch_bounds__(256, 3) void proj_mfma(
    const unsigned short* __restrict__ AOh,
    const unsigned short* __restrict__ Wh, const unsigned short* __restrict__ Wl,
    const float* __restrict__ bo, float* __restrict__ out)
{
    __shared__ __align__(16) unsigned short lds[8192];
    const int tid = threadIdx.x;
    const int lane = tid & 63, lo = lane & 15, h4 = lane >> 4;
    const int w = tid >> 6, wm = w & 1, wn = w >> 1;
    const int row0 = blockIdx.x * 128, col0 = blockIdx.y * 64;

    const unsigned short* sbase =
        (w <= 1) ? AOh + (size_t)row0 * EMB :
        (w == 2) ? Wh  + (size_t)col0 * EMB :
                   Wl  + (size_t)col0 * EMB;
    const int jbase = (w == 1) ? 4 : 0;
    const int soff  = (w <= 1) ? PA_O : (w == 2) ? PWH_O : PWL_O;

    f32x4 acc[4][2];
    #pragma unroll
    for (int i = 0; i < 4; i++)
        #pragma unroll
        for (int j = 0; j < 2; j++) acc[i][j] = (f32x4){0.f, 0.f, 0.f, 0.f};

    for (int k0 = 0; k0 < EMB; k0 += 32) {
        #pragma unroll
        for (int jj = 0; jj < 4; jj++) {
            const int j = jbase + jj;
            const int u = j*64 + lane;
            const int row = u >> 2, c8 = (u & 3) * 8;
            dma16(sbase + (size_t)row * EMB + k0 + c8, &lds[soff + j*512]);
        }
        __syncthreads();

        bf16x8 af[4];
        #pragma unroll
        for (int i = 0; i < 4; i++)
            af[i] = *(const bf16x8*)&lds[PA_O + (64*wm + 16*i + lo)*32 + 8*h4];
        #pragma unroll
        for (int j = 0; j < 2; j++) {
            bf16x8 whf = *(const bf16x8*)&lds[PWH_O + (32*wn + 16*j + lo)*32 + 8*h4];
            bf16x8 wlf = *(const bf16x8*)&lds[PWL_O + (32*wn + 16*j + lo)*32 + 8*h4];
            #pragma unroll
            for (int i = 0; i < 4; i++) {
                acc[i][j] = __builtin_amdgcn_mfma_f32_16x16x32_bf16(af[i], whf, acc[i][j], 0, 0, 0);
                acc[i][j] = __builtin_amdgcn_mfma_f32_16x16x32_bf16(af[i], wlf, acc[i][j], 0, 0, 0);
            }
        }
        __syncthreads();
    }

    #pragma unroll
    for (int i = 0; i < 4; i++)
        #pragma unroll
        for (int r = 0; r < 4; r++) {
            const int sg = row0 + 64*wm + 16*i + 4*h4 + r;
            #pragma unroll
            for (int j = 0; j < 2; j++) {
                const int c = col0 + 32*wn + 16*j + lo;
                out[(size_t)sg * EMB + c] = acc[i][j][r] + bo[c];
            }
        }
}

// ---------------------------------------------------------------------------
// Flash attention v6: R6/R9 body with wave q-tile 16 (was 32), grid 2048.
// VGPR 108@tile32 was grid-limited to 8 waves/CU; halving the tile halves
// register demand (~80 VGPR) and doubles the grid -> 8 blocks/CU x 2 waves
// = 16 waves/CU = 4 waves/SIMD (2x the latency hiding). Identical per-row
// arithmetic/order -> bit-identical absmax. K/V L2 re-reads double (still
// L2-resident, XCD-pinned). LDS 11,072 B/block.
// R7/R8 lessons still apply: no register prefetch, no launch-bounds reg cap.
// ---------------------------------------------------------------------------
__global__ __launch_bounds__(128, 2) void attn_mfma(
    const unsigned short* __restrict__ Qh, const unsigned short* __restrict__ Ql,
    const unsigned short* __restrict__ Kb, const unsigned short* __restrict__ Vt,
    unsigned short* __restrict__ AOh)
{
    __shared__ __align__(16) unsigned short lds[5536];  // P 2x1152 sh | Cbuf 1600f + Lbuf 16f
    const int id   = blockIdx.x;
    const int bh   = 2*(id & 7) + ((id >> 3) & 1);   // XCD-pinned: 2 heads per XCD
    const int q0   = (id >> 4) * 16;                 // 128 q-tiles of 16 rows
    const int tid  = threadIdx.x;                    // 0..127
    const int wk   = tid >> 6;                       // k-half
    const int lane = tid & 63;
    const int lo   = lane & 15;
    const int h4   = lane >> 4;

    // Q fragments register-resident (both waves load the same 16 q-rows)
    bf16x8 qhf[3], qlf[3];
    {
        const size_t qoff = ((size_t)bh*SEQ + q0 + lo) * HD + 8*h4;
        #pragma unroll
        for (int ks = 0; ks < 3; ks++) {
            qhf[ks] = *(const bf16x8*)&Qh[qoff + 32*ks];
            qlf[ks] = *(const bf16x8*)&Ql[qoff + 32*ks];
        }
    }

    f32x4 O[6];
    #pragma unroll
    for (int i = 0; i < 6; i++) O[i] = (f32x4){0.f, 0.f, 0.f, 0.f};
    float lsum[4] = {};

    unsigned short* Pw = lds + wk * 1152;            // wave-private [16][72]
    const unsigned short* KbH = Kb + (size_t)bh * SEQ * HD;
    const unsigned short* VtH = Vt + (size_t)bh * HD * SEQ;

    #pragma unroll 1
    for (int c = 0; c < 16; c++) {
        const int k0 = (wk * 16 + c) * 64;
        const unsigned short* KbG = KbH + (size_t)k0 * HD;
        const unsigned short* VtG = VtH + k0;

        bf16x8 vf[2][6];
        #pragma unroll
        for (int ks2 = 0; ks2 < 2; ks2++)
            #pragma unroll
            for (int nb2 = 0; nb2 < 6; nb2++)
                vf[ks2][nb2] = *(const bf16x8*)&VtG[(size_t)(16*nb2 + lo)*SEQ + 32*ks2 + 8*h4];

        f32x4 S[4];
        #pragma unroll
        for (int nb = 0; nb < 4; nb++) S[nb] = (f32x4){0.f, 0.f, 0.f, 0.f};
        #pragma unroll
        for (int ks = 0; ks < 3; ks++) {
            bf16x8 kf[4];
            #pragma unroll
            for (int nb = 0; nb < 4; nb++)
                kf[nb] = *(const bf16x8*)&KbG[(size_t)(16*nb + lo)*HD + 32*ks + 8*h4];
            #pragma unroll
            for (int nb = 0; nb < 4; nb++) {
                S[nb] = __builtin_amdgcn_mfma_f32_16x16x32_bf16(qhf[ks], kf[nb], S[nb], 0, 0, 0);
                S[nb] = __builtin_amdgcn_mfma_f32_16x16x32_bf16(qlf[ks], kf[nb], S[nb], 0, 0, 0);
            }
        }

        #pragma unroll
        for (int nb = 0; nb < 4; nb++)
            #pragma unroll
            for (int r = 0; r < 4; r++) {
                float p = __expf(S[nb][r]);
                lsum[r] += p;
                Pw[(4*h4 + r)*72 + 16*nb + lo] = f2bf(p);
            }

        #pragma unroll
        for (int ks2 = 0; ks2 < 2; ks2++) {
            bf16x8 pf = *(const bf16x8*)&Pw[(lo)*72 + 32*ks2 + 8*h4];
            #pragma unroll
            for (int nb2 = 0; nb2 < 6; nb2++)
                O[nb2] = __builtin_amdgcn_mfma_f32_16x16x32_bf16(pf, vf[ks2][nb2], O[nb2], 0, 0, 0);
        }
    }

    // ---- split-K combine (single barrier) ----
    float lred[4];
    #pragma unroll
    for (int r = 0; r < 4; r++) {
        float l = lsum[r];
        l += __shfl_xor(l, 1);
        l += __shfl_xor(l, 2);
        l += __shfl_xor(l, 4);
        l += __shfl_xor(l, 8);
        lred[r] = l;
    }

    float* Cbuf = (float*)(lds + 2304);   // [16][100]
    float* Lbuf = Cbuf + 1600;            // [16]
    if (wk == 1) {
        #pragma unroll
        for (int r = 0; r < 4; r++) {
            const int row = 4*h4 + r;
            if (lo == 0) Lbuf[row] = lred[r];
            #pragma unroll
            for (int nb2 = 0; nb2 < 6; nb2++)
                Cbuf[row*100 + 16*nb2 + lo] = O[nb2][r];
        }
    }
    __syncthreads();
    if (wk == 0) {
        const int b = bh >> 3, hh = bh & 7;
        #pragma unroll
        for (int r = 0; r < 4; r++) {
            const int row = 4*h4 + r;
            const float lt = lred[r] + Lbuf[row];
            const float sc = SCALING / lt;
            const size_t base = ((size_t)b*SEQ + q0 + row)*EMB + hh*HD + lo;
            #pragma unroll
            for (int nb2 = 0; nb2 < 6; nb2++)
                AOh[base + 16*nb2] =
                    f2bf((O[nb2][r] + Cbuf[row*100 + 16*nb2 + lo]) * sc);
        }
    }
}

// ---------------------------------------------------------------------------
extern "C" void kernel_launch(void* const* d_in, const int* in_sizes, int n_in,
                              void* d_out, int out_size, void* d_ws, size_t ws_size,
                              hipStream_t stream)
{
    const float* x  = (const float*)d_in[0];
    const float* Wq = (const float*)d_in[1];
    const float* bq = (const float*)d_in[2];
    const float* Wk = (const float*)d_in[3];
    const float* bk = (const float*)d_in[4];
    const float* Wv = (const float*)d_in[5];
    const float* bv = (const float*)d_in[6];
    const float* Wo = (const float*)d_in[7];
    const float* bo = (const float*)d_in[8];
    float* out = (float*)d_out;

    unsigned short* ws = (unsigned short*)d_ws;
    const size_t HS = (size_t)16 * SEQ * HD;       // 3,145,728 shorts
    const size_t WS1 = (size_t)EMB * EMB;          // 589,824
    unsigned short* Qh  = ws;
    unsigned short* Ql  = ws + HS;
    unsigned short* Kb  = ws + 2*HS;
    unsigned short* Vt  = ws + 3*HS;
    unsigned short* xh  = ws + 4*HS;               // dead after qkv -> AOh
    unsigned short* xl  = ws + 5*HS;
    unsigned short* WhT = ws + 6*HS;
    unsigned short* WlT = ws + 6*HS + 4*WS1;
    unsigned short* AOh = xh;

    convert_x<<<1536, 256, 0, stream>>>(x, xh, xl);
    convert_wT<<<dim3(12, 12, 4), 256, 0, stream>>>(Wq, Wk, Wv, Wo, WhT, WlT);
    qkv_mfma<<<dim3(32, 6, 3), 256, 0, stream>>>(xh, xl, WhT, WlT, bq, bk, bv,
                                                 Qh, Ql, Kb, Vt);
    attn_mfma<<<2048, 128, 0, stream>>>(Qh, Ql, Kb, Vt, AOh);
    proj_mfma<<<dim3(32, 12), 256, 0, stream>>>(AOh, WhT + 3*WS1, WlT + 3*WS1, bo, out);
}

// Round 11
// 235.504 us; speedup vs baseline: 1.2832x; 1.2832x over previous
//
#include <hip/hip_runtime.h>
#include <hip/hip_bf16.h>

#define EMB 768
#define HD 96
#define NH 8
#define SEQ 2048
#define SCALING 0.10206207261596575f   // 96^-0.5

typedef short bf16x8 __attribute__((ext_vector_type(8)));
typedef float f32x4  __attribute__((ext_vector_type(4)));
typedef unsigned short u16v8 __attribute__((ext_vector_type(8)));
typedef unsigned short u16v4 __attribute__((ext_vector_type(4)));

union F4 { float4 v; float f[4]; };

__device__ __forceinline__ unsigned short f2bf(float v) {
    __hip_bfloat16 b = __float2bfloat16(v);
    return *reinterpret_cast<unsigned short*>(&b);
}
__device__ __forceinline__ float bf2f(unsigned short u) {
    __hip_bfloat16 b = *reinterpret_cast<__hip_bfloat16*>(&u);
    return __bfloat162float(b);
}

// async global->LDS DMA, 16 B/lane. LDS dest = wave-uniform base + lane*16.
__device__ __forceinline__ void dma16(const unsigned short* g, unsigned short* l) {
    __builtin_amdgcn_global_load_lds(
        (const __attribute__((address_space(1))) unsigned int*)g,
        (__attribute__((address_space(3))) unsigned int*)l,
        16, 0, 0);
}

// ---------------------------------------------------------------------------
// convert_x: fp32 x -> hi/lo bf16 arrays [4096][768].
// ---------------------------------------------------------------------------
__global__ __launch_bounds__(256) void convert_x(
    const float* __restrict__ x,
    unsigned short* __restrict__ xh, unsigned short* __restrict__ xl)
{
    const size_t i0 = ((size_t)blockIdx.x * 256 + threadIdx.x) * 8;
    F4 a, b;
    a.v = *(const float4*)&x[i0];
    b.v = *(const float4*)&x[i0 + 4];
    u16v8 h, l;
    #pragma unroll
    for (int j = 0; j < 4; j++) {
        unsigned short hu = f2bf(a.f[j]);
        h[j] = hu; l[j] = f2bf(a.f[j] - bf2f(hu));
    }
    #pragma unroll
    for (int j = 0; j < 4; j++) {
        unsigned short hu = f2bf(b.f[j]);
        h[4+j] = hu; l[4+j] = f2bf(b.f[j] - bf2f(hu));
    }
    *(u16v8*)&xh[i0] = h;
    *(u16v8*)&xl[i0] = l;
}

// ---------------------------------------------------------------------------
// convert_wT: W [768 k][768 n] fp32 -> W^T hi/lo bf16 [mat][768 n][768 k].
// ---------------------------------------------------------------------------
__global__ __launch_bounds__(256) void convert_wT(
    const float* __restrict__ Wq, const float* __restrict__ Wk,
    const float* __restrict__ Wv, const float* __restrict__ Wo,
    unsigned short* __restrict__ WhT, unsigned short* __restrict__ WlT)
{
    const int z = blockIdx.z;
    const float* W = (z == 0) ? Wq : (z == 1) ? Wk : (z == 2) ? Wv : Wo;
    unsigned short* oh = WhT + (size_t)z * 589824;
    unsigned short* ol = WlT + (size_t)z * 589824;
    __shared__ float T[64][68];
    const int t = threadIdx.x;
    const int r = t >> 2, cg = (t & 3) * 16;
    const int k0 = blockIdx.x * 64, n0 = blockIdx.y * 64;
    #pragma unroll
    for (int i = 0; i < 4; i++) {
        float4 v = *(const float4*)&W[(size_t)(k0 + r) * EMB + n0 + cg + 4*i];
        *(float4*)&T[r][cg + 4*i] = v;
    }
    __syncthreads();
    #pragma unroll
    for (int i = 0; i < 4; i++) {
        u16v4 h, l;
        #pragma unroll
        for (int j = 0; j < 4; j++) {
            float v = T[cg + 4*i + j][r];
            unsigned short hu = f2bf(v);
            h[j] = hu; l[j] = f2bf(v - bf2f(hu));
        }
        *(u16v4*)&oh[(size_t)(n0 + r) * EMB + k0 + cg + 4*i] = h;
        *(u16v4*)&ol[(size_t)(n0 + r) * EMB + k0 + cg + 4*i] = l;
    }
}

// ---------------------------------------------------------------------------
// qkv_mfma v2 (unchanged from R9): global_load_lds staging, 128x128, BK=32.
// Q (z=0): 3-term -> hi/lo bf16 out. K (z=1): 2-term -> single bf16.
// V (z=2): 2-term -> bf16 transposed [bh][d][s].
// ---------------------------------------------------------------------------
#define QA_H 0
#define QA_L 4096
#define QW_H 8192
#define QW_L 12288

__global__ __launch_bounds__(256, 3) void qkv_mfma(
    const unsigned short* __restrict__ xh, const unsigned short* __restrict__ xl,
    const unsigned short* __restrict__ WhT, const unsigned short* __restrict__ WlT,
    const float* __restrict__ bq, const float* __restrict__ bk, const float* __restrict__ bv,
    unsigned short* __restrict__ Qh, unsigned short* __restrict__ Ql,
    unsigned short* __restrict__ Kb, unsigned short* __restrict__ Vt)
{
    const int which = blockIdx.z;
    const unsigned short* Wh = WhT + (size_t)which * 589824;
    const unsigned short* Wl = WlT + (size_t)which * 589824;
    const float* bias = (which == 0) ? bq : (which == 1) ? bk : bv;

    __shared__ __align__(16) unsigned short lds[16384];
    const int tid = threadIdx.x;
    const int lane = tid & 63, lo = lane & 15, h4 = lane >> 4;
    const int w = tid >> 6, wm = w & 1, wn = w >> 1;
    const int row0 = blockIdx.x * 128, col0 = blockIdx.y * 128;

    const unsigned short* sbase =
        (w == 0) ? xh + (size_t)row0 * EMB :
        (w == 1) ? xl + (size_t)row0 * EMB :
        (w == 2) ? Wh + (size_t)col0 * EMB :
                   Wl + (size_t)col0 * EMB;
    const int soff = w * 4096;

    f32x4 acc[4][4];
    #pragma unroll
    for (int i = 0; i < 4; i++)
        #pragma unroll
        for (int j = 0; j < 4; j++) acc[i][j] = (f32x4){0.f, 0.f, 0.f, 0.f};

    const int wlane = lane;

    for (int k0 = 0; k0 < EMB; k0 += 32) {
        #pragma unroll
        for (int j = 0; j < 8; j++) {
            const int u = j*64 + wlane;
            const int row = u >> 2, c8 = (u & 3) * 8;
            dma16(sbase + (size_t)row * EMB + k0 + c8, &lds[soff + j*512]);
        }
        __syncthreads();

        bf16x8 ah[4], al[4];
        #pragma unroll
        for (int i = 0; i < 4; i++)
            ah[i] = *(const bf16x8*)&lds[QA_H + (64*wm + 16*i + lo)*32 + 8*h4];
        if (which <= 1) {
            #pragma unroll
            for (int i = 0; i < 4; i++)
                al[i] = *(const bf16x8*)&lds[QA_L + (64*wm + 16*i + lo)*32 + 8*h4];
        }
        #pragma unroll
        for (int j = 0; j < 4; j++) {
            bf16x8 whf = *(const bf16x8*)&lds[QW_H + (64*wn + 16*j + lo)*32 + 8*h4];
            #pragma unroll
            for (int i = 0; i < 4; i++)
                acc[i][j] = __builtin_amdgcn_mfma_f32_16x16x32_bf16(ah[i], whf, acc[i][j], 0, 0, 0);
            if (which <= 1) {
                #pragma unroll
                for (int i = 0; i < 4; i++)
                    acc[i][j] = __builtin_amdgcn_mfma_f32_16x16x32_bf16(al[i], whf, acc[i][j], 0, 0, 0);
            }
            if (which != 1) {
                bf16x8 wlf = *(const bf16x8*)&lds[QW_L + (64*wn + 16*j + lo)*32 + 8*h4];
                #pragma unroll
                for (int i = 0; i < 4; i++)
                    acc[i][j] = __builtin_amdgcn_mfma_f32_16x16x32_bf16(ah[i], wlf, acc[i][j], 0, 0, 0);
            }
        }
        __syncthreads();
    }

    if (which == 0) {
        #pragma unroll
        for (int i = 0; i < 4; i++)
            #pragma unroll
            for (int r = 0; r < 4; r++) {
                const int sg = row0 + 64*wm + 16*i + 4*h4 + r;
                const int b = sg >> 11, s = sg & 2047;
                #pragma unroll
                for (int j = 0; j < 4; j++) {
                    const int c = col0 + 64*wn + 16*j + lo;
                    const int h = c / HD, d = c - h*HD;
                    float v = acc[i][j][r] + bias[c];
                    unsigned short hu = f2bf(v);
                    const size_t base = ((size_t)(b*NH + h) * SEQ + s) * HD + d;
                    Qh[base] = hu;
                    Ql[base] = f2bf(v - bf2f(hu));
                }
            }
    } else if (which == 1) {
        #pragma unroll
        for (int i = 0; i < 4; i++)
            #pragma unroll
            for (int r = 0; r < 4; r++) {
                const int sg = row0 + 64*wm + 16*i + 4*h4 + r;
                const int b = sg >> 11, s = sg & 2047;
                #pragma unroll
                for (int j = 0; j < 4; j++) {
                    const int c = col0 + 64*wn + 16*j + lo;
                    const int h = c / HD, d = c - h*HD;
                    float v = acc[i][j][r] + bias[c];
                    Kb[((size_t)(b*NH + h) * SEQ + s) * HD + d] = f2bf(v);
                }
            }
    } else {
        #pragma unroll
        for (int i = 0; i < 4; i++)
            #pragma unroll
            for (int r = 0; r < 4; r++) {
                const int sg = row0 + 64*wm + 16*i + 4*h4 + r;
                const int b = sg >> 11, s = sg & 2047;
                #pragma unroll
                for (int j = 0; j < 4; j++) {
                    const int c = col0 + 64*wn + 16*j + lo;
                    const int h = c / HD, d = c - h*HD;
                    float v = acc[i][j][r] + bias[c];
                    Vt[((size_t)(b*NH + h) * HD + d) * SEQ + s] = f2bf(v);
                }
            }
    }
}

// ---------------------------------------------------------------------------
// proj_mfma v2 (unchanged from R9): 128x64 tile, DMA staging, 2-term.
// ---------------------------------------------------------------------------
#define PA_O 0
#define PWH_O 4096
#define PWL_O 6144

__global__ __launch_bounds__(256, 3) void proj_mfma(
    const unsigned short* __restrict__ AOh,
    const unsigned short* __restrict__ Wh, const unsigned short* __restrict__ Wl,
    const float* __restrict__ bo, float* __restrict__ out)
{
    __shared__ __align__(16) unsigned short lds[8192];
    const int tid = threadIdx.x;
    const int lane = tid & 63, lo = lane & 15, h4 = lane >> 4;
    const int w = tid >> 6, wm = w & 1, wn = w >> 1;
    const int row0 = blockIdx.x * 128, col0 = blockIdx.y * 64;

    const unsigned short* sbase =
        (w <= 1) ? AOh + (size_t)row0 * EMB :
        (w == 2) ? Wh  + (size_t)col0 * EMB :
                   Wl  + (size_t)col0 * EMB;
    const int jbase = (w == 1) ? 4 : 0;
    const int soff  = (w <= 1) ? PA_O : (w == 2) ? PWH_O : PWL_O;

    f32x4 acc[4][2];
    #pragma unroll
    for (int i = 0; i < 4; i++)
        #pragma unroll
        for (int j = 0; j < 2; j++) acc[i][j] = (f32x4){0.f, 0.f, 0.f, 0.f};

    for (int k0 = 0; k0 < EMB; k0 += 32) {
        #pragma unroll
        for (int jj = 0; jj < 4; jj++) {
            const int j = jbase + jj;
            const int u = j*64 + lane;
            const int row = u >> 2, c8 = (u & 3) * 8;
            dma16(sbase + (size_t)row * EMB + k0 + c8, &lds[soff + j*512]);
        }
        __syncthreads();

        bf16x8 af[4];
        #pragma unroll
        for (int i = 0; i < 4; i++)
            af[i] = *(const bf16x8*)&lds[PA_O + (64*wm + 16*i + lo)*32 + 8*h4];
        #pragma unroll
        for (int j = 0; j < 2; j++) {
            bf16x8 whf = *(const bf16x8*)&lds[PWH_O + (32*wn + 16*j + lo)*32 + 8*h4];
            bf16x8 wlf = *(const bf16x8*)&lds[PWL_O + (32*wn + 16*j + lo)*32 + 8*h4];
            #pragma unroll
            for (int i = 0; i < 4; i++) {
                acc[i][j] = __builtin_amdgcn_mfma_f32_16x16x32_bf16(af[i], whf, acc[i][j], 0, 0, 0);
                acc[i][j] = __builtin_amdgcn_mfma_f32_16x16x32_bf16(af[i], wlf, acc[i][j], 0, 0, 0);
            }
        }
        __syncthreads();
    }

    #pragma unroll
    for (int i = 0; i < 4; i++)
        #pragma unroll
        for (int r = 0; r < 4; r++) {
            const int sg = row0 + 64*wm + 16*i + 4*h4 + r;
            #pragma unroll
            for (int j = 0; j < 2; j++) {
                const int c = col0 + 32*wn + 16*j + lo;
                out[(size_t)sg * EMB + c] = acc[i][j][r] + bo[c];
            }
        }
}

// ---------------------------------------------------------------------------
// Flash attention v7 = R8's 4-way split-K structure with the launch-bounds
// defect fixed: __launch_bounds__(256, 2) (reg cap 256) instead of (256, 4)
// (reg cap 128 -> R8's spill disaster). Body is the proven R6/R9 chunk
// (VGPR 108); 4 waves x 108 = 432 <= 512 -> 4 waves/SIMD from actual usage.
// 1024 blocks x 256 thr -> 4 blocks/CU x 4 waves = 16 waves/CU, 8 chunks/wave
// (half R9's serial chain), K/V traffic unchanged vs R9.
// Tile-16 (R10) falsified: halving MFMA-per-load loses more than TLP gains.
// ---------------------------------------------------------------------------
__global__ __launch_bounds__(256, 2) void attn_mfma(
    const unsigned short* __restrict__ Qh, const unsigned short* __restrict__ Ql,
    const unsigned short* __restrict__ Kb, const unsigned short* __restrict__ Vt,
    unsigned short* __restrict__ AOh)
{
    __shared__ __align__(16) unsigned short lds[12928];
    const int id   = blockIdx.x;
    const int bh   = 2*(id & 7) + ((id >> 3) & 1);   // XCD-pinned: 2 heads/XCD
    const int q0   = (id >> 4) * 32;
    const int tid  = threadIdx.x;                    // 0..255
    const int wk   = tid >> 6;                       // k-quarter 0..3
    const int lane = tid & 63;
    const int lo   = lane & 15;
    const int h4   = lane >> 4;

    bf16x8 qhf[2][3], qlf[2][3];
    #pragma unroll
    for (int mi = 0; mi < 2; mi++) {
        const size_t qoff = ((size_t)bh*SEQ + q0 + 16*mi + lo) * HD + 8*h4;
        #pragma unroll
        for (int ks = 0; ks < 3; ks++) {
            qhf[mi][ks] = *(const bf16x8*)&Qh[qoff + 32*ks];
            qlf[mi][ks] = *(const bf16x8*)&Ql[qoff + 32*ks];
        }
    }

    f32x4 O[2][6];
    #pragma unroll
    for (int mi = 0; mi < 2; mi++)
        #pragma unroll
        for (int i = 0; i < 6; i++) O[mi][i] = (f32x4){0.f, 0.f, 0.f, 0.f};
    float lsum[2][4] = {};

    unsigned short* Pw = lds + wk * 2304;            // wave-private [32][72]
    const unsigned short* KbH = Kb + (size_t)bh * SEQ * HD;
    const unsigned short* VtH = Vt + (size_t)bh * HD * SEQ;

    #pragma unroll 1
    for (int c = 0; c < 8; c++) {
        const int k0 = (wk * 8 + c) * 64;
        const unsigned short* KbG = KbH + (size_t)k0 * HD;
        const unsigned short* VtG = VtH + k0;

        bf16x8 vf[2][6];
        #pragma unroll
        for (int ks2 = 0; ks2 < 2; ks2++)
            #pragma unroll
            for (int nb2 = 0; nb2 < 6; nb2++)
                vf[ks2][nb2] = *(const bf16x8*)&VtG[(size_t)(16*nb2 + lo)*SEQ + 32*ks2 + 8*h4];

        f32x4 S[2][4];
        #pragma unroll
        for (int mi = 0; mi < 2; mi++)
            #pragma unroll
            for (int nb = 0; nb < 4; nb++) S[mi][nb] = (f32x4){0.f, 0.f, 0.f, 0.f};
        #pragma unroll
        for (int ks = 0; ks < 3; ks++) {
            bf16x8 kf[4];
            #pragma unroll
            for (int nb = 0; nb < 4; nb++)
                kf[nb] = *(const bf16x8*)&KbG[(size_t)(16*nb + lo)*HD + 32*ks + 8*h4];
            #pragma unroll
            for (int nb = 0; nb < 4; nb++)
                #pragma unroll
                for (int mi = 0; mi < 2; mi++) {
                    S[mi][nb] = __builtin_amdgcn_mfma_f32_16x16x32_bf16(qhf[mi][ks], kf[nb], S[mi][nb], 0, 0, 0);
                    S[mi][nb] = __builtin_amdgcn_mfma_f32_16x16x32_bf16(qlf[mi][ks], kf[nb], S[mi][nb], 0, 0, 0);
                }
        }

        #pragma unroll
        for (int mi = 0; mi < 2; mi++)
            #pragma unroll
            for (int nb = 0; nb < 4; nb++)
                #pragma unroll
                for (int r = 0; r < 4; r++) {
                    float p = __expf(S[mi][nb][r]);
                    lsum[mi][r] += p;
                    Pw[(16*mi + 4*h4 + r)*72 + 16*nb + lo] = f2bf(p);
                }

        #pragma unroll
        for (int ks2 = 0; ks2 < 2; ks2++) {
            bf16x8 pf0 = *(const bf16x8*)&Pw[(lo)*72      + 32*ks2 + 8*h4];
            bf16x8 pf1 = *(const bf16x8*)&Pw[(16 + lo)*72 + 32*ks2 + 8*h4];
            #pragma unroll
            for (int nb2 = 0; nb2 < 6; nb2++) {
                O[0][nb2] = __builtin_amdgcn_mfma_f32_16x16x32_bf16(pf0, vf[ks2][nb2], O[0][nb2], 0, 0, 0);
                O[1][nb2] = __builtin_amdgcn_mfma_f32_16x16x32_bf16(pf1, vf[ks2][nb2], O[1][nb2], 0, 0, 0);
            }
        }
    }

    // per-wave row-sum reduce
    float lred[2][4];
    #pragma unroll
    for (int mi = 0; mi < 2; mi++)
        #pragma unroll
        for (int r = 0; r < 4; r++) {
            float l = lsum[mi][r];
            l += __shfl_xor(l, 1);
            l += __shfl_xor(l, 2);
            l += __shfl_xor(l, 4);
            l += __shfl_xor(l, 8);
            lred[mi][r] = l;
        }

    // 4-way combine tree (Cbuf/Lbuf alias the dead P region after barrier 1)
    float* Cbuf = (float*)lds;          // [2][32][100]
    float* Lb   = Cbuf + 6400;          // [2][32]
    __syncthreads();                    // all waves done with P
    if (wk >= 2) {
        float* C = Cbuf + (wk - 2) * 3200;
        float* L = Lb   + (wk - 2) * 32;
        #pragma unroll
        for (int mi = 0; mi < 2; mi++)
            #pragma unroll
            for (int r = 0; r < 4; r++) {
                const int row = 16*mi + 4*h4 + r;
                if (lo == 0) L[row] = lred[mi][r];
                #pragma unroll
                for (int nb2 = 0; nb2 < 6; nb2++)
                    C[row*100 + 16*nb2 + lo] = O[mi][nb2][r];
            }
    }
    __syncthreads();
    if (wk < 2) {
        float* C = Cbuf + wk * 3200;
        float* L = Lb   + wk * 32;
        #pragma unroll
        for (int mi = 0; mi < 2; mi++)
            #pragma unroll
            for (int r = 0; r < 4; r++) {
                const int row = 16*mi + 4*h4 + r;
                lred[mi][r] += L[row];
                #pragma unroll
                for (int nb2 = 0; nb2 < 6; nb2++)
                    O[mi][nb2][r] += C[row*100 + 16*nb2 + lo];
            }
    }
    __syncthreads();
    if (wk == 1) {
        #pragma unroll
        for (int mi = 0; mi < 2; mi++)
            #pragma unroll
            for (int r = 0; r < 4; r++) {
                const int row = 16*mi + 4*h4 + r;
                if (lo == 0) Lb[row] = lred[mi][r];
                #pragma unroll
                for (int nb2 = 0; nb2 < 6; nb2++)
                    Cbuf[row*100 + 16*nb2 + lo] = O[mi][nb2][r];
            }
    }
    __syncthreads();
    if (wk == 0) {
        const int b = bh >> 3, hh = bh & 7;
        #pragma unroll
        for (int mi = 0; mi < 2; mi++)
            #pragma unroll
            for (int r = 0; r < 4; r++) {
                const int row = 16*mi + 4*h4 + r;
                const float lt = lred[mi][r] + Lb[row];
                const float sc = SCALING / lt;
                const size_t base = ((size_t)b*SEQ + q0 + row)*EMB + hh*HD + lo;
                #pragma unroll
                for (int nb2 = 0; nb2 < 6; nb2++)
                    AOh[base + 16*nb2] =
                        f2bf((O[mi][nb2][r] + Cbuf[row*100 + 16*nb2 + lo]) * sc);
            }
    }
}

// ---------------------------------------------------------------------------
extern "C" void kernel_launch(void* const* d_in, const int* in_sizes, int n_in,
                              void* d_out, int out_size, void* d_ws, size_t ws_size,
                              hipStream_t stream)
{
    const float* x  = (const float*)d_in[0];
    const float* Wq = (const float*)d_in[1];
    const float* bq = (const float*)d_in[2];
    const float* Wk = (const float*)d_in[3];
    const float* bk = (const float*)d_in[4];
    const float* Wv = (const float*)d_in[5];
    const float* bv = (const float*)d_in[6];
    const float* Wo = (const float*)d_in[7];
    const float* bo = (const float*)d_in[8];
    float* out = (float*)d_out;

    unsigned short* ws = (unsigned short*)d_ws;
    const size_t HS = (size_t)16 * SEQ * HD;       // 3,145,728 shorts
    const size_t WS1 = (size_t)EMB * EMB;          // 589,824
    unsigned short* Qh  = ws;
    unsigned short* Ql  = ws + HS;
    unsigned short* Kb  = ws + 2*HS;
    unsigned short* Vt  = ws + 3*HS;
    unsigned short* xh  = ws + 4*HS;               // dead after qkv -> AOh
    unsigned short* xl  = ws + 5*HS;
    unsigned short* WhT = ws + 6*HS;
    unsigned short* WlT = ws + 6*HS + 4*WS1;
    unsigned short* AOh = xh;

    convert_x<<<1536, 256, 0, stream>>>(x, xh, xl);
    convert_wT<<<dim3(12, 12, 4), 256, 0, stream>>>(Wq, Wk, Wv, Wo, WhT, WlT);
    qkv_mfma<<<dim3(32, 6, 3), 256, 0, stream>>>(xh, xl, WhT, WlT, bq, bk, bv,
                                                 Qh, Ql, Kb, Vt);
    attn_mfma<<<1024, 256, 0, stream>>>(Qh, Ql, Kb, Vt, AOh);
    proj_mfma<<<dim3(32, 12), 256, 0, stream>>>(AOh, WhT + 3*WS1, WlT + 3*WS1, bo, out);
}

// Round 12
// 216.259 us; speedup vs baseline: 1.3974x; 1.0890x over previous
//
#include <hip/hip_runtime.h>
#include <hip/hip_bf16.h>

#define EMB 768
#define HD 96
#define NH 8
#define SEQ 2048
#define SCALING 0.10206207261596575f   // 96^-0.5

typedef short bf16x8 __attribute__((ext_vector_type(8)));
typedef float f32x4  __attribute__((ext_vector_type(4)));
typedef unsigned short u16v8 __attribute__((ext_vector_type(8)));
typedef unsigned short u16v4 __attribute__((ext_vector_type(4)));

union F4 { float4 v; float f[4]; };

__device__ __forceinline__ unsigned short f2bf(float v) {
    __hip_bfloat16 b = __float2bfloat16(v);
    return *reinterpret_cast<unsigned short*>(&b);
}
__device__ __forceinline__ float bf2f(unsigned short u) {
    __hip_bfloat16 b = *reinterpret_cast<__hip_bfloat16*>(&u);
    return __bfloat162float(b);
}

// async global->LDS DMA, 16 B/lane. LDS dest = wave-uniform base + lane*16.
__device__ __forceinline__ void dma16(const unsigned short* g, unsigned short* l) {
    __builtin_amdgcn_global_load_lds(
        (const __attribute__((address_space(1))) unsigned int*)g,
        (__attribute__((address_space(3))) unsigned int*)l,
        16, 0, 0);
}

// ---------------------------------------------------------------------------
// convert_x: fp32 x -> hi/lo bf16 arrays [4096][768].
// ---------------------------------------------------------------------------
__global__ __launch_bounds__(256) void convert_x(
    const float* __restrict__ x,
    unsigned short* __restrict__ xh, unsigned short* __restrict__ xl)
{
    const size_t i0 = ((size_t)blockIdx.x * 256 + threadIdx.x) * 8;
    F4 a, b;
    a.v = *(const float4*)&x[i0];
    b.v = *(const float4*)&x[i0 + 4];
    u16v8 h, l;
    #pragma unroll
    for (int j = 0; j < 4; j++) {
        unsigned short hu = f2bf(a.f[j]);
        h[j] = hu; l[j] = f2bf(a.f[j] - bf2f(hu));
    }
    #pragma unroll
    for (int j = 0; j < 4; j++) {
        unsigned short hu = f2bf(b.f[j]);
        h[4+j] = hu; l[4+j] = f2bf(b.f[j] - bf2f(hu));
    }
    *(u16v8*)&xh[i0] = h;
    *(u16v8*)&xl[i0] = l;
}

// ---------------------------------------------------------------------------
// convert_wT: W [768 k][768 n] fp32 -> W^T hi/lo bf16 [mat][768 n][768 k].
// ---------------------------------------------------------------------------
__global__ __launch_bounds__(256) void convert_wT(
    const float* __restrict__ Wq, const float* __restrict__ Wk,
    const float* __restrict__ Wv, const float* __restrict__ Wo,
    unsigned short* __restrict__ WhT, unsigned short* __restrict__ WlT)
{
    const int z = blockIdx.z;
    const float* W = (z == 0) ? Wq : (z == 1) ? Wk : (z == 2) ? Wv : Wo;
    unsigned short* oh = WhT + (size_t)z * 589824;
    unsigned short* ol = WlT + (size_t)z * 589824;
    __shared__ float T[64][68];
    const int t = threadIdx.x;
    const int r = t >> 2, cg = (t & 3) * 16;
    const int k0 = blockIdx.x * 64, n0 = blockIdx.y * 64;
    #pragma unroll
    for (int i = 0; i < 4; i++) {
        float4 v = *(const float4*)&W[(size_t)(k0 + r) * EMB + n0 + cg + 4*i];
        *(float4*)&T[r][cg + 4*i] = v;
    }
    __syncthreads();
    #pragma unroll
    for (int i = 0; i < 4; i++) {
        u16v4 h, l;
        #pragma unroll
        for (int j = 0; j < 4; j++) {
            float v = T[cg + 4*i + j][r];
            unsigned short hu = f2bf(v);
            h[j] = hu; l[j] = f2bf(v - bf2f(hu));
        }
        *(u16v4*)&oh[(size_t)(n0 + r) * EMB + k0 + cg + 4*i] = h;
        *(u16v4*)&ol[(size_t)(n0 + r) * EMB + k0 + cg + 4*i] = l;
    }
}

// ---------------------------------------------------------------------------
// qkv_mfma v2 (unchanged from R9): global_load_lds staging, 128x128, BK=32.
// Q (z=0): 3-term -> hi/lo bf16 out. K (z=1): 2-term -> single bf16.
// V (z=2): 2-term -> bf16 transposed [bh][d][s].
// ---------------------------------------------------------------------------
#define QA_H 0
#define QA_L 4096
#define QW_H 8192
#define QW_L 12288

__global__ __launch_bounds__(256, 3) void qkv_mfma(
    const unsigned short* __restrict__ xh, const unsigned short* __restrict__ xl,
    const unsigned short* __restrict__ WhT, const unsigned short* __restrict__ WlT,
    const float* __restrict__ bq, const float* __restrict__ bk, const float* __restrict__ bv,
    unsigned short* __restrict__ Qh, unsigned short* __restrict__ Ql,
    unsigned short* __restrict__ Kb, unsigned short* __restrict__ Vt)
{
    const int which = blockIdx.z;
    const unsigned short* Wh = WhT + (size_t)which * 589824;
    const unsigned short* Wl = WlT + (size_t)which * 589824;
    const float* bias = (which == 0) ? bq : (which == 1) ? bk : bv;

    __shared__ __align__(16) unsigned short lds[16384];
    const int tid = threadIdx.x;
    const int lane = tid & 63, lo = lane & 15, h4 = lane >> 4;
    const int w = tid >> 6, wm = w & 1, wn = w >> 1;
    const int row0 = blockIdx.x * 128, col0 = blockIdx.y * 128;

    const unsigned short* sbase =
        (w == 0) ? xh + (size_t)row0 * EMB :
        (w == 1) ? xl + (size_t)row0 * EMB :
        (w == 2) ? Wh + (size_t)col0 * EMB :
                   Wl + (size_t)col0 * EMB;
    const int soff = w * 4096;

    f32x4 acc[4][4];
    #pragma unroll
    for (int i = 0; i < 4; i++)
        #pragma unroll
        for (int j = 0; j < 4; j++) acc[i][j] = (f32x4){0.f, 0.f, 0.f, 0.f};

    for (int k0 = 0; k0 < EMB; k0 += 32) {
        #pragma unroll
        for (int j = 0; j < 8; j++) {
            const int u = j*64 + lane;
            const int row = u >> 2, c8 = (u & 3) * 8;
            dma16(sbase + (size_t)row * EMB + k0 + c8, &lds[soff + j*512]);
        }
        __syncthreads();

        bf16x8 ah[4], al[4];
        #pragma unroll
        for (int i = 0; i < 4; i++)
            ah[i] = *(const bf16x8*)&lds[QA_H + (64*wm + 16*i + lo)*32 + 8*h4];
        if (which <= 1) {
            #pragma unroll
            for (int i = 0; i < 4; i++)
                al[i] = *(const bf16x8*)&lds[QA_L + (64*wm + 16*i + lo)*32 + 8*h4];
        }
        #pragma unroll
        for (int j = 0; j < 4; j++) {
            bf16x8 whf = *(const bf16x8*)&lds[QW_H + (64*wn + 16*j + lo)*32 + 8*h4];
            #pragma unroll
            for (int i = 0; i < 4; i++)
                acc[i][j] = __builtin_amdgcn_mfma_f32_16x16x32_bf16(ah[i], whf, acc[i][j], 0, 0, 0);
            if (which <= 1) {
                #pragma unroll
                for (int i = 0; i < 4; i++)
                    acc[i][j] = __builtin_amdgcn_mfma_f32_16x16x32_bf16(al[i], whf, acc[i][j], 0, 0, 0);
            }
            if (which != 1) {
                bf16x8 wlf = *(const bf16x8*)&lds[QW_L + (64*wn + 16*j + lo)*32 + 8*h4];
                #pragma unroll
                for (int i = 0; i < 4; i++)
                    acc[i][j] = __builtin_amdgcn_mfma_f32_16x16x32_bf16(ah[i], wlf, acc[i][j], 0, 0, 0);
            }
        }
        __syncthreads();
    }

    if (which == 0) {
        #pragma unroll
        for (int i = 0; i < 4; i++)
            #pragma unroll
            for (int r = 0; r < 4; r++) {
                const int sg = row0 + 64*wm + 16*i + 4*h4 + r;
                const int b = sg >> 11, s = sg & 2047;
                #pragma unroll
                for (int j = 0; j < 4; j++) {
                    const int c = col0 + 64*wn + 16*j + lo;
                    const int h = c / HD, d = c - h*HD;
                    float v = acc[i][j][r] + bias[c];
                    unsigned short hu = f2bf(v);
                    const size_t base = ((size_t)(b*NH + h) * SEQ + s) * HD + d;
                    Qh[base] = hu;
                    Ql[base] = f2bf(v - bf2f(hu));
                }
            }
    } else if (which == 1) {
        #pragma unroll
        for (int i = 0; i < 4; i++)
            #pragma unroll
            for (int r = 0; r < 4; r++) {
                const int sg = row0 + 64*wm + 16*i + 4*h4 + r;
                const int b = sg >> 11, s = sg & 2047;
                #pragma unroll
                for (int j = 0; j < 4; j++) {
                    const int c = col0 + 64*wn + 16*j + lo;
                    const int h = c / HD, d = c - h*HD;
                    float v = acc[i][j][r] + bias[c];
                    Kb[((size_t)(b*NH + h) * SEQ + s) * HD + d] = f2bf(v);
                }
            }
    } else {
        #pragma unroll
        for (int i = 0; i < 4; i++)
            #pragma unroll
            for (int r = 0; r < 4; r++) {
                const int sg = row0 + 64*wm + 16*i + 4*h4 + r;
                const int b = sg >> 11, s = sg & 2047;
                #pragma unroll
                for (int j = 0; j < 4; j++) {
                    const int c = col0 + 64*wn + 16*j + lo;
                    const int h = c / HD, d = c - h*HD;
                    float v = acc[i][j][r] + bias[c];
                    Vt[((size_t)(b*NH + h) * HD + d) * SEQ + s] = f2bf(v);
                }
            }
    }
}

// ---------------------------------------------------------------------------
// proj_mfma v2 (unchanged from R9): 128x64 tile, DMA staging, 2-term.
// ---------------------------------------------------------------------------
#define PA_O 0
#define PWH_O 4096
#define PWL_O 6144

__global__ __launch_bounds__(256, 3) void proj_mfma(
    const unsigned short* __restrict__ AOh,
    const unsigned short* __restrict__ Wh, const unsigned short* __restrict__ Wl,
    const float* __restrict__ bo, float* __restrict__ out)
{
    __shared__ __align__(16) unsigned short lds[8192];
    const int tid = threadIdx.x;
    const int lane = tid & 63, lo = lane & 15, h4 = lane >> 4;
    const int w = tid >> 6, wm = w & 1, wn = w >> 1;
    const int row0 = blockIdx.x * 128, col0 = blockIdx.y * 64;

    const unsigned short* sbase =
        (w <= 1) ? AOh + (size_t)row0 * EMB :
        (w == 2) ? Wh  + (size_t)col0 * EMB :
                   Wl  + (size_t)col0 * EMB;
    const int jbase = (w == 1) ? 4 : 0;
    const int soff  = (w <= 1) ? PA_O : (w == 2) ? PWH_O : PWL_O;

    f32x4 acc[4][2];
    #pragma unroll
    for (int i = 0; i < 4; i++)
        #pragma unroll
        for (int j = 0; j < 2; j++) acc[i][j] = (f32x4){0.f, 0.f, 0.f, 0.f};

    for (int k0 = 0; k0 < EMB; k0 += 32) {
        #pragma unroll
        for (int jj = 0; jj < 4; jj++) {
            const int j = jbase + jj;
            const int u = j*64 + lane;
            const int row = u >> 2, c8 = (u & 3) * 8;
            dma16(sbase + (size_t)row * EMB + k0 + c8, &lds[soff + j*512]);
        }
        __syncthreads();

        bf16x8 af[4];
        #pragma unroll
        for (int i = 0; i < 4; i++)
            af[i] = *(const bf16x8*)&lds[PA_O + (64*wm + 16*i + lo)*32 + 8*h4];
        #pragma unroll
        for (int j = 0; j < 2; j++) {
            bf16x8 whf = *(const bf16x8*)&lds[PWH_O + (32*wn + 16*j + lo)*32 + 8*h4];
            bf16x8 wlf = *(const bf16x8*)&lds[PWL_O + (32*wn + 16*j + lo)*32 + 8*h4];
            #pragma unroll
            for (int i = 0; i < 4; i++) {
                acc[i][j] = __builtin_amdgcn_mfma_f32_16x16x32_bf16(af[i], whf, acc[i][j], 0, 0, 0);
                acc[i][j] = __builtin_amdgcn_mfma_f32_16x16x32_bf16(af[i], wlf, acc[i][j], 0, 0, 0);
            }
        }
        __syncthreads();
    }

    #pragma unroll
    for (int i = 0; i < 4; i++)
        #pragma unroll
        for (int r = 0; r < 4; r++) {
            const int sg = row0 + 64*wm + 16*i + 4*h4 + r;
            #pragma unroll
            for (int j = 0; j < 2; j++) {
                const int c = col0 + 32*wn + 16*j + lo;
                out[(size_t)sg * EMB + c] = acc[i][j][r] + bo[c];
            }
        }
}

// ---------------------------------------------------------------------------
// Flash attention v8: K/V reuse via LDS (the load-count lever).
// Evidence: time ∝ global-load instrs (R9 786k=83us vs R10 1.57M=160us).
// Block = 4 waves x 32 q-rows = 128 q (4x fewer K/V re-reads than R9);
// grid = 16 bh x 16 q-tiles = 256 blocks (1/CU, tail-free, XCD-pinned).
// K/V double-buffered in padded LDS (K [64][104], V [96][72] -- R5-proven
// 2-way-free layouts); per thread per chunk: 6 u16v8 global loads (prefetched
// one full chunk ahead) + 6 b128 LDS writes. ONE barrier per chunk.
// No split-K -> no combine; each wave owns its q-rows end-to-end.
// Per-wave compute body = R9's proven sequence (2-term QK, no-max-shift
// softmax, P via wave-private LDS rows).
// LDS: 2x(13312+13824) + 4x4608 = 72,704 B. launch_bounds(256,1): no reg cap
// (R8 lesson); 1 block/CU so occupancy ~12% is EXPECTED (LDS-pipe-bound
// design, not TLP-bound).
// ---------------------------------------------------------------------------
#define AKB0 0            // K buf A [64][104]
#define AVB0 6656         // V buf A [96][72]
#define ABUF 13568        // shorts per K+V buffer pair
#define AP_OFF 27136      // P: 4 waves x [32][72]

__global__ __launch_bounds__(256, 1) void attn_mfma(
    const unsigned short* __restrict__ Qh, const unsigned short* __restrict__ Ql,
    const unsigned short* __restrict__ Kb, const unsigned short* __restrict__ Vt,
    unsigned short* __restrict__ AOh)
{
    __shared__ __align__(16) unsigned short lds[36352];
    const int id   = blockIdx.x;
    const int xcd  = id & 7;
    const int j    = id >> 3;                 // 0..31
    const int bh   = 2*xcd + (j & 1);         // 2 heads per XCD
    const int q0   = (j >> 1) * 128;          // 16 q-tiles of 128 rows
    const int tid  = threadIdx.x;             // 0..255
    const int w    = tid >> 6;                // wave: owns q rows [32w, 32w+32)
    const int lane = tid & 63;
    const int lo   = lane & 15;
    const int h4   = lane >> 4;

    // Q fragments register-resident for this wave's 32 rows
    bf16x8 qhf[2][3], qlf[2][3];
    #pragma unroll
    for (int mi = 0; mi < 2; mi++) {
        const size_t qoff = ((size_t)bh*SEQ + q0 + 32*w + 16*mi + lo) * HD + 8*h4;
        #pragma unroll
        for (int ks = 0; ks < 3; ks++) {
            qhf[mi][ks] = *(const bf16x8*)&Qh[qoff + 32*ks];
            qlf[mi][ks] = *(const bf16x8*)&Ql[qoff + 32*ks];
        }
    }

    f32x4 O[2][6];
    #pragma unroll
    for (int mi = 0; mi < 2; mi++)
        #pragma unroll
        for (int i = 0; i < 6; i++) O[mi][i] = (f32x4){0.f, 0.f, 0.f, 0.f};
    float lsum[2][4] = {};

    unsigned short* Pw = lds + AP_OFF + w * 2304;     // wave-private [32][72]
    const unsigned short* KbH = Kb + (size_t)bh * SEQ * HD;
    const unsigned short* VtH = Vt + (size_t)bh * HD * SEQ;

    // ---- stage chunk 0 into buffer 0 ----
    #pragma unroll
    for (int r = 0; r < 3; r++) {
        const int u = tid + 256*r;                    // 0..767
        const int kk = u / 12, g = u - kk*12;         // K: 64 rows x 12 groups
        *(u16v8*)&lds[AKB0 + kk*104 + 8*g] = *(const u16v8*)&KbH[kk*HD + 8*g];
        const int dV = u >> 3, c8 = u & 7;            // V: 96 rows x 8 groups
        *(u16v8*)&lds[AVB0 + dV*72 + 8*c8] = *(const u16v8*)&VtH[(size_t)dV*SEQ + 8*c8];
    }
    __syncthreads();

    #pragma unroll 1
    for (int c = 0; c < 32; c++) {
        unsigned short* curK = lds + (c & 1) * ABUF;
        unsigned short* curV = curK + 6656;
        unsigned short* nxtK = lds + ((c + 1) & 1) * ABUF;
        unsigned short* nxtV = nxtK + 6656;
        const int kn = (c + 1 < 32) ? (c + 1) * 64 : 0;   // tail clamp (write is dead)

        // ---- prefetch next chunk into regs (consumed at end of this chunk) ----
        u16v8 kst[3], vst[3];
        {
            const unsigned short* KG = KbH + (size_t)kn * HD;
            const unsigned short* VG = VtH + kn;
            #pragma unroll
            for (int r = 0; r < 3; r++) {
                const int u = tid + 256*r;
                const int kk = u / 12, g = u - kk*12;
                kst[r] = *(const u16v8*)&KG[kk*HD + 8*g];
                const int dV = u >> 3, c8 = u & 7;
                vst[r] = *(const u16v8*)&VG[(size_t)dV*SEQ + 8*c8];
            }
        }

        // ---- S = Q K^T from LDS (2-term split) ----
        f32x4 S[2][4];
        #pragma unroll
        for (int mi = 0; mi < 2; mi++)
            #pragma unroll
            for (int nb = 0; nb < 4; nb++) S[mi][nb] = (f32x4){0.f, 0.f, 0.f, 0.f};
        #pragma unroll
        for (int ks = 0; ks < 3; ks++) {
            bf16x8 kf[4];
            #pragma unroll
            for (int nb = 0; nb < 4; nb++)
                kf[nb] = *(const bf16x8*)&curK[(16*nb + lo)*104 + 32*ks + 8*h4];
            #pragma unroll
            for (int nb = 0; nb < 4; nb++)
                #pragma unroll
                for (int mi = 0; mi < 2; mi++) {
                    S[mi][nb] = __builtin_amdgcn_mfma_f32_16x16x32_bf16(qhf[mi][ks], kf[nb], S[mi][nb], 0, 0, 0);
                    S[mi][nb] = __builtin_amdgcn_mfma_f32_16x16x32_bf16(qlf[mi][ks], kf[nb], S[mi][nb], 0, 0, 0);
                }
        }

        // ---- P = exp(S), partial row-sums, P -> wave-private LDS ----
        #pragma unroll
        for (int mi = 0; mi < 2; mi++)
            #pragma unroll
            for (int nb = 0; nb < 4; nb++)
                #pragma unroll
                for (int r = 0; r < 4; r++) {
                    float p = __expf(S[mi][nb][r]);
                    lsum[mi][r] += p;
                    Pw[(16*mi + 4*h4 + r)*72 + 16*nb + lo] = f2bf(p);
                }

        // ---- O += P V from LDS ----
        #pragma unroll
        for (int ks2 = 0; ks2 < 2; ks2++) {
            bf16x8 pf0 = *(const bf16x8*)&Pw[(lo)*72      + 32*ks2 + 8*h4];
            bf16x8 pf1 = *(const bf16x8*)&Pw[(16 + lo)*72 + 32*ks2 + 8*h4];
            #pragma unroll
            for (int nb2 = 0; nb2 < 6; nb2++) {
                bf16x8 vfv = *(const bf16x8*)&curV[(16*nb2 + lo)*72 + 32*ks2 + 8*h4];
                O[0][nb2] = __builtin_amdgcn_mfma_f32_16x16x32_bf16(pf0, vfv, O[0][nb2], 0, 0, 0);
                O[1][nb2] = __builtin_amdgcn_mfma_f32_16x16x32_bf16(pf1, vfv, O[1][nb2], 0, 0, 0);
            }
        }

        // ---- write prefetched regs to the other buffer ----
        #pragma unroll
        for (int r = 0; r < 3; r++) {
            const int u = tid + 256*r;
            const int kk = u / 12, g = u - kk*12;
            *(u16v8*)&nxtK[kk*104 + 8*g] = kst[r];
            const int dV = u >> 3, c8 = u & 7;
            *(u16v8*)&nxtV[dV*72 + 8*c8] = vst[r];
        }
        __syncthreads();
    }

    // ---- epilogue: per-wave direct store (no combine) ----
    const int b = bh >> 3, hh = bh & 7;
    #pragma unroll
    for (int mi = 0; mi < 2; mi++)
        #pragma unroll
        for (int r = 0; r < 4; r++) {
            float l = lsum[mi][r];
            l += __shfl_xor(l, 1);
            l += __shfl_xor(l, 2);
            l += __shfl_xor(l, 4);
            l += __shfl_xor(l, 8);
            const float sc = SCALING / l;
            const int q = q0 + 32*w + 16*mi + 4*h4 + r;
            const size_t base = ((size_t)b*SEQ + q)*EMB + hh*HD + lo;
            #pragma unroll
            for (int nb2 = 0; nb2 < 6; nb2++)
                AOh[base + 16*nb2] = f2bf(O[mi][nb2][r] * sc);
        }
}

// ---------------------------------------------------------------------------
extern "C" void kernel_launch(void* const* d_in, const int* in_sizes, int n_in,
                              void* d_out, int out_size, void* d_ws, size_t ws_size,
                              hipStream_t stream)
{
    const float* x  = (const float*)d_in[0];
    const float* Wq = (const float*)d_in[1];
    const float* bq = (const float*)d_in[2];
    const float* Wk = (const float*)d_in[3];
    const float* bk = (const float*)d_in[4];
    const float* Wv = (const float*)d_in[5];
    const float* bv = (const float*)d_in[6];
    const float* Wo = (const float*)d_in[7];
    const float* bo = (const float*)d_in[8];
    float* out = (float*)d_out;

    unsigned short* ws = (unsigned short*)d_ws;
    const size_t HS = (size_t)16 * SEQ * HD;       // 3,145,728 shorts
    const size_t WS1 = (size_t)EMB * EMB;          // 589,824
    unsigned short* Qh  = ws;
    unsigned short* Ql  = ws + HS;
    unsigned short* Kb  = ws + 2*HS;
    unsigned short* Vt  = ws + 3*HS;
    unsigned short* xh  = ws + 4*HS;               // dead after qkv -> AOh
    unsigned short* xl  = ws + 5*HS;
    unsigned short* WhT = ws + 6*HS;
    unsigned short* WlT = ws + 6*HS + 4*WS1;
    unsigned short* AOh = xh;

    convert_x<<<1536, 256, 0, stream>>>(x, xh, xl);
    convert_wT<<<dim3(12, 12, 4), 256, 0, stream>>>(Wq, Wk, Wv, Wo, WhT, WlT);
    qkv_mfma<<<dim3(32, 6, 3), 256, 0, stream>>>(xh, xl, WhT, WlT, bq, bk, bv,
                                                 Qh, Ql, Kb, Vt);
    attn_mfma<<<256, 256, 0, stream>>>(Qh, Ql, Kb, Vt, AOh);
    proj_mfma<<<dim3(32, 12), 256, 0, stream>>>(AOh, WhT + 3*WS1, WlT + 3*WS1, bo, out);
}